// Round 1
// baseline (3653.852 us; speedup 1.0000x reference)
//
#include <hip/hip_runtime.h>

#define T_DIM 8
#define F_DIM 64

// Kernel 1: scatter-add edge features into agg[(N,8)] with hardware f32 atomics.
// Each thread handles 4 consecutive edges (float4 loads per t).
__global__ __launch_bounds__(256) void scatter_agg_kernel(
    const unsigned* __restrict__ idx, const float* __restrict__ ef,
    float* __restrict__ agg, int E) {
  // Detect int64 vs int32 index dtype: for int64 (values < 2^18) every odd
  // 32-bit word (high half) is 0; for int32 odd words are random col indices.
  __shared__ int s_is64;
  if (threadIdx.x == 0) {
    unsigned acc = 0;
#pragma unroll
    for (int i = 1; i < 64; i += 2) acc |= idx[i];
    s_is64 = (acc == 0) ? 1 : 0;
  }
  __syncthreads();
  const bool is64 = (s_is64 != 0);

  const long long base =
      ((long long)blockIdx.x * blockDim.x + threadIdx.x) * 4;
  if (base >= E) return;

  int rows[4];
  if (is64) {
#pragma unroll
    for (int j = 0; j < 4; ++j) rows[j] = (int)idx[(size_t)(base + j) << 2];
  } else {
#pragma unroll
    for (int j = 0; j < 4; ++j) rows[j] = (int)idx[(size_t)(base + j) << 1];
  }

  float4 v[T_DIM];
#pragma unroll
  for (int t = 0; t < T_DIM; ++t)
    v[t] = *(const float4*)(ef + (size_t)t * E + base);

#pragma unroll
  for (int j = 0; j < 4; ++j) {
    float* dst = agg + (size_t)rows[j] * T_DIM;
#pragma unroll
    for (int t = 0; t < T_DIM; ++t) {
      unsafeAtomicAdd(dst + t, ((const float*)&v[t])[j]);
    }
  }
}

// Kernel 2: out[n, :] = agg[n, :] @ kernel(8,64) + bias. 16 threads per row,
// each computes 4 consecutive f (float4 store). kernel+bias staged in LDS.
__global__ __launch_bounds__(256) void mm_kernel(
    const float* __restrict__ agg, const float* __restrict__ kern,
    const float* __restrict__ bias, float* __restrict__ out, int N) {
  __shared__ float sK[T_DIM * F_DIM];
  __shared__ float sB[F_DIM];
  const int tid = threadIdx.x;
  if (tid < (T_DIM * F_DIM / 4))
    ((float4*)sK)[tid] = ((const float4*)kern)[tid];
  if (tid < F_DIM / 4)
    ((float4*)sB)[tid] = ((const float4*)bias)[tid];
  __syncthreads();

  const long long gid = (long long)blockIdx.x * blockDim.x + tid;
  const int n = (int)(gid >> 4);
  if (n >= N) return;
  const int q = (int)(gid & 15);

  const float4 a0 = *(const float4*)(agg + (size_t)n * T_DIM);
  const float4 a1 = *(const float4*)(agg + (size_t)n * T_DIM + 4);
  const float a[T_DIM] = {a0.x, a0.y, a0.z, a0.w, a1.x, a1.y, a1.z, a1.w};

  float4 r = ((const float4*)sB)[q];
#pragma unroll
  for (int t = 0; t < T_DIM; ++t) {
    const float4 kv = ((const float4*)sK)[t * (F_DIM / 4) + q];
    r.x += a[t] * kv.x;
    r.y += a[t] * kv.y;
    r.z += a[t] * kv.z;
    r.w += a[t] * kv.w;
  }
  *(float4*)(out + (size_t)n * F_DIM + (q << 2)) = r;
}

extern "C" void kernel_launch(void* const* d_in, const int* in_sizes, int n_in,
                              void* d_out, int out_size, void* d_ws,
                              size_t ws_size, hipStream_t stream) {
  const float* ef = (const float*)d_in[0];
  const unsigned* idx = (const unsigned*)d_in[1];
  const float* kern = (const float*)d_in[3];
  const float* bias = (const float*)d_in[4];
  float* out = (float*)d_out;

  const int E = in_sizes[1] / 2;        // logical edge count (E,2)
  const int N = out_size / F_DIM;       // 262144
  float* agg = (float*)d_ws;            // (N, 8) f32 = 8 MB

  hipMemsetAsync(agg, 0, (size_t)N * T_DIM * sizeof(float), stream);

  const int threads1 = E / 4;           // 4 edges per thread
  scatter_agg_kernel<<<(threads1 + 255) / 256, 256, 0, stream>>>(idx, ef, agg,
                                                                 E);

  const long long threads2 = (long long)N * 16;  // 16 threads per output row
  mm_kernel<<<(int)((threads2 + 255) / 256), 256, 0, stream>>>(agg, kern, bias,
                                                               out, N);
}

// Round 2
// 1085.813 us; speedup vs baseline: 3.3651x; 3.3651x over previous
//
#include <hip/hip_runtime.h>

typedef unsigned int uint;

#define T_DIM 8
#define F_DIM 64
#define BUCKETS 256      // N/BUCKETS = 1024 rows per bucket (N = 262144)
#define RPB 1024         // rows per bucket
#define RPB_SHIFT 10
#define K1_BLOCKS 512    // edge chunks: E/512 = 16384 edges per block

// ---------- fast path ----------

// K1: per-block LDS histogram of 256 buckets, merged into global totals.
__global__ __launch_bounds__(256) void count_kernel(
    const uint* __restrict__ idx, uint* __restrict__ totals, int E) {
  __shared__ uint hist[BUCKETS];
  __shared__ int s_is64;
  const int tid = threadIdx.x;
  if (tid == 0) {  // int64 indices have zero high words (values < 2^18)
    uint acc = 0;
    for (int i = 1; i < 64; i += 2) acc |= idx[i];
    s_is64 = (acc == 0);
  }
  if (tid < BUCKETS) hist[tid] = 0;
  __syncthreads();
  const bool is64 = (s_is64 != 0);
  const int chunk = E / K1_BLOCKS;
  const int start = blockIdx.x * chunk;
  for (int i = tid; i < chunk; i += 256) {
    const uint e = start + i;
    const uint row = is64 ? idx[(size_t)e << 2] : idx[(size_t)e << 1];
    atomicAdd(&hist[row >> RPB_SHIFT], 1u);
  }
  __syncthreads();
  if (tid < BUCKETS) atomicAdd(&totals[tid], hist[tid]);
}

// K2: exclusive scan of 256 totals -> base[257] and cursor[256].
__global__ __launch_bounds__(256) void scan_kernel(
    const uint* __restrict__ totals, uint* __restrict__ base,
    uint* __restrict__ cursor) {
  __shared__ uint s[BUCKETS];
  const int tid = threadIdx.x;
  const uint mine = totals[tid];
  s[tid] = mine;
  __syncthreads();
  for (int off = 1; off < BUCKETS; off <<= 1) {
    const uint v = (tid >= off) ? s[tid - off] : 0;
    __syncthreads();
    s[tid] += v;
    __syncthreads();
  }
  const uint excl = s[tid] - mine;
  base[tid] = excl;
  cursor[tid] = excl;
  if (tid == BUCKETS - 1) base[BUCKETS] = s[tid];
}

// K3: scatter (row, ef[0..7]) records into bucket-contiguous regions.
__global__ __launch_bounds__(256) void scatter_bin_kernel(
    const uint* __restrict__ idx, const float* __restrict__ ef,
    uint* __restrict__ cursor, uint* __restrict__ rows_out,
    float4* __restrict__ recs_lo, float4* __restrict__ recs_hi, int E) {
  __shared__ uint hist[BUCKETS];
  __shared__ uint bbase[BUCKETS];
  __shared__ int s_is64;
  const int tid = threadIdx.x;
  if (tid == 0) {
    uint acc = 0;
    for (int i = 1; i < 64; i += 2) acc |= idx[i];
    s_is64 = (acc == 0);
  }
  if (tid < BUCKETS) hist[tid] = 0;
  __syncthreads();
  const bool is64 = (s_is64 != 0);
  const int chunk = E / K1_BLOCKS;
  const int start = blockIdx.x * chunk;
  // pass 1: local histogram
  for (int i = tid; i < chunk; i += 256) {
    const uint e = start + i;
    const uint row = is64 ? idx[(size_t)e << 2] : idx[(size_t)e << 1];
    atomicAdd(&hist[row >> RPB_SHIFT], 1u);
  }
  __syncthreads();
  // reserve slots per bucket; reuse hist as the local cursor
  if (tid < BUCKETS) {
    bbase[tid] = atomicAdd(&cursor[tid], hist[tid]);
    hist[tid] = 0;
  }
  __syncthreads();
  // pass 2: write records
  for (int i = tid; i < chunk; i += 256) {
    const uint e = start + i;
    const uint row = is64 ? idx[(size_t)e << 2] : idx[(size_t)e << 1];
    const uint bkt = row >> RPB_SHIFT;
    const uint slot = bbase[bkt] + atomicAdd(&hist[bkt], 1u);
    float v[T_DIM];
#pragma unroll
    for (int t = 0; t < T_DIM; ++t) v[t] = ef[(size_t)t * E + e];
    rows_out[slot] = row;
    recs_lo[slot] = make_float4(v[0], v[1], v[2], v[3]);
    recs_hi[slot] = make_float4(v[4], v[5], v[6], v[7]);
  }
}

// K4: one block per bucket — accumulate records into padded LDS tile
// (stride 9 breaks the stride-8 bank pattern), then fused matmul + bias.
__global__ __launch_bounds__(1024) void accum_mm_kernel(
    const uint* __restrict__ rows, const float4* __restrict__ recs_lo,
    const float4* __restrict__ recs_hi, const uint* __restrict__ base,
    const float* __restrict__ kern, const float* __restrict__ bias,
    float* __restrict__ out) {
  __shared__ float sAgg[RPB * 9];
  __shared__ float sK[T_DIM * F_DIM];
  __shared__ float sB[F_DIM];
  const int tid = threadIdx.x;
  const int b = blockIdx.x;
  for (int i = tid; i < RPB * 9; i += 1024) sAgg[i] = 0.f;
  if (tid < T_DIM * F_DIM / 4) ((float4*)sK)[tid] = ((const float4*)kern)[tid];
  if (tid < F_DIM / 4) ((float4*)sB)[tid] = ((const float4*)bias)[tid];
  __syncthreads();
  const uint s = base[b], e = base[b + 1];
  for (uint i = s + tid; i < e; i += 1024) {
    const uint r = rows[i] & (RPB - 1);
    const float4 lo = recs_lo[i];
    const float4 hi = recs_hi[i];
    float* p = &sAgg[r * 9];
    atomicAdd(p + 0, lo.x);
    atomicAdd(p + 1, lo.y);
    atomicAdd(p + 2, lo.z);
    atomicAdd(p + 3, lo.w);
    atomicAdd(p + 4, hi.x);
    atomicAdd(p + 5, hi.y);
    atomicAdd(p + 6, hi.z);
    atomicAdd(p + 7, hi.w);
  }
  __syncthreads();
  // matmul: RPB rows × 16 float4-chunks of F
  const uint base_row = (uint)b << RPB_SHIFT;
  for (int w = tid; w < RPB * 16; w += 1024) {
    const int r = w >> 4, q = w & 15;
    const float* a = &sAgg[r * 9];
    float4 acc = ((const float4*)sB)[q];
#pragma unroll
    for (int t = 0; t < T_DIM; ++t) {
      const float4 kv = ((const float4*)sK)[t * 16 + q];
      const float av = a[t];
      acc.x += av * kv.x;
      acc.y += av * kv.y;
      acc.z += av * kv.z;
      acc.w += av * kv.w;
    }
    *(float4*)(out + (size_t)(base_row + r) * F_DIM + (q << 2)) = acc;
  }
}

// ---------- fallback path (round-1 atomic version) ----------

__global__ __launch_bounds__(256) void scatter_agg_kernel(
    const uint* __restrict__ idx, const float* __restrict__ ef,
    float* __restrict__ agg, int E) {
  __shared__ int s_is64;
  if (threadIdx.x == 0) {
    uint acc = 0;
    for (int i = 1; i < 64; i += 2) acc |= idx[i];
    s_is64 = (acc == 0) ? 1 : 0;
  }
  __syncthreads();
  const bool is64 = (s_is64 != 0);
  const long long base = ((long long)blockIdx.x * blockDim.x + threadIdx.x) * 4;
  if (base >= E) return;
  int rows[4];
  if (is64) {
#pragma unroll
    for (int j = 0; j < 4; ++j) rows[j] = (int)idx[(size_t)(base + j) << 2];
  } else {
#pragma unroll
    for (int j = 0; j < 4; ++j) rows[j] = (int)idx[(size_t)(base + j) << 1];
  }
  float4 v[T_DIM];
#pragma unroll
  for (int t = 0; t < T_DIM; ++t)
    v[t] = *(const float4*)(ef + (size_t)t * E + base);
#pragma unroll
  for (int j = 0; j < 4; ++j) {
    float* dst = agg + (size_t)rows[j] * T_DIM;
#pragma unroll
    for (int t = 0; t < T_DIM; ++t)
      unsafeAtomicAdd(dst + t, ((const float*)&v[t])[j]);
  }
}

__global__ __launch_bounds__(256) void mm_kernel(
    const float* __restrict__ agg, const float* __restrict__ kern,
    const float* __restrict__ bias, float* __restrict__ out, int N) {
  __shared__ float sK[T_DIM * F_DIM];
  __shared__ float sB[F_DIM];
  const int tid = threadIdx.x;
  if (tid < (T_DIM * F_DIM / 4)) ((float4*)sK)[tid] = ((const float4*)kern)[tid];
  if (tid < F_DIM / 4) ((float4*)sB)[tid] = ((const float4*)bias)[tid];
  __syncthreads();
  const long long gid = (long long)blockIdx.x * blockDim.x + tid;
  const int n = (int)(gid >> 4);
  if (n >= N) return;
  const int q = (int)(gid & 15);
  const float4 a0 = *(const float4*)(agg + (size_t)n * T_DIM);
  const float4 a1 = *(const float4*)(agg + (size_t)n * T_DIM + 4);
  const float a[T_DIM] = {a0.x, a0.y, a0.z, a0.w, a1.x, a1.y, a1.z, a1.w};
  float4 r = ((const float4*)sB)[q];
#pragma unroll
  for (int t = 0; t < T_DIM; ++t) {
    const float4 kv = ((const float4*)sK)[t * (F_DIM / 4) + q];
    r.x += a[t] * kv.x;
    r.y += a[t] * kv.y;
    r.z += a[t] * kv.z;
    r.w += a[t] * kv.w;
  }
  *(float4*)(out + (size_t)n * F_DIM + (q << 2)) = r;
}

extern "C" void kernel_launch(void* const* d_in, const int* in_sizes, int n_in,
                              void* d_out, int out_size, void* d_ws,
                              size_t ws_size, hipStream_t stream) {
  const float* ef = (const float*)d_in[0];
  const uint* idx = (const uint*)d_in[1];
  const float* kern = (const float*)d_in[3];
  const float* bias = (const float*)d_in[4];
  float* out = (float*)d_out;

  const int E = in_sizes[1] / 2;   // logical edge count (E,2)
  const int N = out_size / F_DIM;  // 262144

  // workspace carve-out
  size_t off = 0;
  auto carve = [&](size_t bytes) {
    void* p = (char*)d_ws + off;
    off += (bytes + 255) & ~(size_t)255;
    return p;
  };
  float4* recs_lo = (float4*)carve((size_t)E * 16);
  float4* recs_hi = (float4*)carve((size_t)E * 16);
  uint* rows = (uint*)carve((size_t)E * 4);
  uint* totals = (uint*)carve(BUCKETS * 4);
  uint* base = (uint*)carve((BUCKETS + 1) * 4);
  uint* cursor = (uint*)carve(BUCKETS * 4);

  const bool fast = (E == (K1_BLOCKS * 16384)) && (N == BUCKETS * RPB) &&
                    (off <= ws_size);
  if (fast) {
    hipMemsetAsync(totals, 0, BUCKETS * sizeof(uint), stream);
    count_kernel<<<K1_BLOCKS, 256, 0, stream>>>(idx, totals, E);
    scan_kernel<<<1, 256, 0, stream>>>(totals, base, cursor);
    scatter_bin_kernel<<<K1_BLOCKS, 256, 0, stream>>>(idx, ef, cursor, rows,
                                                      recs_lo, recs_hi, E);
    accum_mm_kernel<<<BUCKETS, 1024, 0, stream>>>(rows, recs_lo, recs_hi, base,
                                                  kern, bias, out);
  } else {
    float* agg = (float*)d_ws;  // (N, 8) f32
    hipMemsetAsync(agg, 0, (size_t)N * T_DIM * sizeof(float), stream);
    scatter_agg_kernel<<<(E / 4 + 255) / 256, 256, 0, stream>>>(idx, ef, agg,
                                                                E);
    mm_kernel<<<(int)(((long long)N * 16 + 255) / 256), 256, 0, stream>>>(
        agg, kern, bias, out, N);
  }
}